// Round 16
// baseline (151.506 us; speedup 1.0000x reference)
//
#include <hip/hip_runtime.h>

#define NUM_GRAPHS 64
#define NSC 160                 // sub-chunks; N = 100000 = 160 * 625
#define SCN 625                 // nodes per sub-chunk (10-bit local id)
#define XPAD 628                // padded facc stride (mult of 4)
#define SB 512                  // bin blocks (2 blocks/CU)
#define CAP 128                 // records per (bin-block, sub-chunk); mean 78, +5.7 sigma
#define SEGSTRIDE (NSC * CAP)   // record-region stride per segment
#define PBREC 12800             // per-block record buffer (2*6250 = 12500)
#define BITER 8                 // max grid-stride iters in bin (8*1024 >= 6250)
#define FSCALE 32768.0f         // fixed-point force scale (2^15)
#define FINV   (1.0f / 32768.0f)

// ---------------------------------------------------------------------------
// P1: two-pass LDS counting-sort bin with register-cached endpoints (proven
// R13/R15, with fused pack + energy/accumulator zeroing in the prologue).
// Record: own_loc(10b)|other(17b)<<10|eflag<<27.
__global__ __launch_bounds__(1024, 8) void bin_kernel(
    const float* __restrict__ pos, const int* __restrict__ batch,
    float4* __restrict__ pos4, float* __restrict__ energy,
    int* __restrict__ gx,                  // [N] global int force-x acc
    unsigned long long* __restrict__ gyz,  // [N] global u64 force-yz acc
    const int* __restrict__ ei,            // [2,E]
    unsigned int* __restrict__ recs,       // [SB][NSC][CAP]
    int* __restrict__ counts,              // [SB][NSC]
    int N, int E, int per_block)
{
    __shared__ unsigned int buf[PBREC];      // 50.0 KB
    __shared__ int hist[NSC];
    __shared__ int csr[NSC];
    __shared__ int cursor[NSC];
    __shared__ int scan_s[NSC];

    const int t = threadIdx.x, b = blockIdx.x;
    const int lane = t & 63, w = t >> 6;     // 16 waves
    const int e0 = b * per_block, e1 = min(E, e0 + per_block);

    // fused prologue: pack pos4; zero energy + global int accumulators.
    // All consumed only by LATER dispatches (no intra-kernel ordering needed).
    {
        const int gt = b * 1024 + t;
        if (gt < N) {
            float4 v;
            v.x = pos[3 * gt + 0];
            v.y = pos[3 * gt + 1];
            v.z = pos[3 * gt + 2];
            v.w = __int_as_float(batch[gt]);
            pos4[gt] = v;
            gx[gt] = 0;
            gyz[gt] = 0ull;
        }
        if (b == 0 && t < NUM_GRAPHS) energy[t] = 0.f;
    }

    int civ[BITER], cjv[BITER];              // register-cached endpoints

    for (int i = t; i < NSC; i += 1024) hist[i] = 0;
    __syncthreads();

    // pass 1: histogram (both endpoints); cache iv/jv in registers
    #pragma unroll
    for (int it = 0; it < BITER; ++it) {
        const int e = e0 + t + it * 1024;
        if (e < e1) {
            const int iv = ei[e], jv = ei[E + e];
            civ[it] = iv; cjv[it] = jv;
            atomicAdd(&hist[iv / SCN], 1);
            atomicAdd(&hist[jv / SCN], 1);
        }
    }
    __syncthreads();

    // Hillis-Steele inclusive scan over 160 bins
    if (t < NSC) scan_s[t] = hist[t];
    __syncthreads();
    for (int d = 1; d < NSC; d <<= 1) {
        int v = 0;
        if (t < NSC && t >= d) v = scan_s[t - d];
        __syncthreads();
        if (t < NSC) scan_s[t] += v;
        __syncthreads();
    }
    if (t < NSC) {
        const int excl = scan_s[t] - hist[t];
        csr[t] = excl;
        cursor[t] = excl;
    }
    __syncthreads();

    // pass 2: scatter records into LDS at exact offsets (endpoints from regs)
    #pragma unroll
    for (int it = 0; it < BITER; ++it) {
        const int e = e0 + t + it * 1024;
        if (e < e1) {
            const int iv = civ[it], jv = cjv[it];
            const int si = iv / SCN, sj = jv / SCN;
            const int s1 = atomicAdd(&cursor[si], 1);
            buf[s1] = (unsigned int)(iv - si * SCN) | ((unsigned int)jv << 10) | (1u << 27);
            const int s2 = atomicAdd(&cursor[sj], 1);
            buf[s2] = (unsigned int)(jv - sj * SCN) | ((unsigned int)iv << 10);
        }
    }
    __syncthreads();

    // flush: wave per bin — contiguous LDS reads, coalesced global writes
    unsigned int* dst0 = recs + (size_t)b * NSC * CAP;
    for (int s = w; s < NSC; s += 16) {
        const int base = csr[s];
        const int cnt  = min(hist[s], CAP);
        for (int k = lane; k < cnt; k += 64)
            dst0[s * CAP + k] = buf[base + k];
        if (lane == 0) counts[b * NSC + s] = cnt;
    }
}

// ---------------------------------------------------------------------------
// P2: accumulate — R11/R13's proven drain (x via u32 LDS atomic, y/z packed
// u64; 57us). NEW epilogue: block adds facc directly into the global int
// accumulators with COALESCED global atomics (exact int sums; u64 low-half
// carry behavior identical to the in-block scheme validated since R11),
// eliminating the 19.2MB partials write + the reduce kernel's re-read.
template<int G>
__global__ __launch_bounds__(256, 8) void accumulate_kernel(
    const float4* __restrict__ pos4,
    const unsigned int* __restrict__ recs,
    const int* __restrict__ counts,
    float* __restrict__ energy,            // d_out[0..63], pre-zeroed
    int* __restrict__ gx,                  // [N] global int acc, pre-zeroed
    unsigned long long* __restrict__ gyz)  // [N] global u64 acc, pre-zeroed
{
    __shared__ float4 slab[SCN];
    __shared__ __align__(16) int facc_x[XPAD];
    __shared__ __align__(16) unsigned long long facc_yz[XPAD];
    __shared__ float ered[8];              // 4 waves x {e_lo, e_hi}

    const int t    = threadIdx.x;
    const int lane = t & 63;
    const int w    = t >> 6;               // 4 waves
    const int s    = blockIdx.x % NSC;     // stride-160 -> same XCD (160%8==0)
    const int g    = blockIdx.x / NSC;

    constexpr int SPB   = SB / G;          // segments per block: 32
    constexpr int SPW   = SPB / 4;         // segments per wave:   8
    constexpr int NPASS = (SPW + 7) / 8;   // 8-segment passes:    1

    for (int i = t; i < SCN; i += 256) slab[i] = pos4[s * SCN + i];
    for (int i = 4 * t; i < XPAD; i += 1024) {
        int4 z = {0, 0, 0, 0};
        *(int4*)&facc_x[i] = z;
    }
    for (int i = 4 * t; i < 2 * XPAD; i += 1024) {
        int4 z = {0, 0, 0, 0};
        *(int4*)&((int*)facc_yz)[i] = z;
    }
    __syncthreads();

    const int gmin_i = __float_as_int(slab[0].w);
    float e_lo = 0.f, e_hi = 0.f;          // energy for gmin / gmax

    for (int pass = 0; pass < NPASS; ++pass) {
        const int seg0 = g * SPB + w * SPW + pass * 8;
        int v = (lane < 8) ? counts[(seg0 + lane) * NSC + s] : 0;
        #pragma unroll
        for (int d = 1; d < 8; d <<= 1) {
            const int u = __shfl_up(v, d);
            if (lane >= d) v += u;
        }
        const int b0 = __shfl(v, 0), b1 = __shfl(v, 1), b2 = __shfl(v, 2),
                  b3 = __shfl(v, 3), b4 = __shfl(v, 4), b5 = __shfl(v, 5),
                  b6 = __shfl(v, 6);
        const int tot = __shfl(v, 7);
        const unsigned int* bp = recs + ((size_t)seg0 * NSC + s) * CAP;

        for (int base = 0; base < tot; base += 256) {
            unsigned int rec[4];
            bool  val[4];
            int   a[4];
            float4 pb[4];
            // phase 1: record loads (coalesced within runs)
            #pragma unroll
            for (int u = 0; u < 4; ++u) {
                const int r = base + lane + (u << 6);
                val[u] = r < tot;
                if (val[u]) {
                    const int k = (r >= b0) + (r >= b1) + (r >= b2) + (r >= b3)
                                + (r >= b4) + (r >= b5) + (r >= b6);
                    int prev = 0;
                    prev = (k > 0) ? b0 : prev; prev = (k > 1) ? b1 : prev;
                    prev = (k > 2) ? b2 : prev; prev = (k > 3) ? b3 : prev;
                    prev = (k > 4) ? b4 : prev; prev = (k > 5) ? b5 : prev;
                    prev = (k > 6) ? b6 : prev;
                    rec[u] = bp[(size_t)k * SEGSTRIDE + (r - prev)];
                }
            }
            // phase 2: divergent pos4 gathers (L2-resident)
            #pragma unroll
            for (int u = 0; u < 4; ++u) {
                if (val[u]) {
                    a[u]  = (int)(rec[u] & 1023);
                    pb[u] = pos4[(rec[u] >> 10) & 0x1FFFF];
                }
            }
            // phase 3: compute + 2 int LDS atomics (x u32; y,z packed u64)
            #pragma unroll
            for (int u = 0; u < 4; ++u) {
                if (val[u]) {
                    const float4 pa = slab[a[u]];
                    const float dx = pa.x - pb[u].x;
                    const float dy = pa.y - pb[u].y;
                    const float dz = pa.z - pb[u].z;
                    const float r2  = fmaxf(dx*dx + dy*dy + dz*dz, 1e-24f);
                    const float inv = __builtin_amdgcn_rsqf(r2);  // 1/d
                    const float sc  = 1.0f - inv;                 // delta/d
                    const int xq = __float2int_rn(-sc * dx * FSCALE);
                    const int yq = __float2int_rn(-sc * dy * FSCALE);
                    const int zq = __float2int_rn(-sc * dz * FSCALE);
                    atomicAdd(&facc_x[a[u]], xq);
                    const unsigned long long pk =
                        ((unsigned long long)(unsigned int)zq << 32)
                        + (unsigned long long)(unsigned int)yq;
                    atomicAdd(&facc_yz[a[u]], pk);
                    if (rec[u] >> 27) {                           // energy once/edge
                        const float delta = r2 * inv - 1.0f;      // d - 1
                        const float e = 0.5f * delta * delta;
                        if (__float_as_int(pa.w) == gmin_i) e_lo += e;
                        else                                e_hi += e;
                    }
                }
            }
        }
    }

    // block-reduce the two energy registers; 2 global atomics per block
    #pragma unroll
    for (int d = 32; d > 0; d >>= 1) {
        e_lo += __shfl_down(e_lo, d);
        e_hi += __shfl_down(e_hi, d);
    }
    if (lane == 0) { ered[2 * w] = e_lo; ered[2 * w + 1] = e_hi; }

    __syncthreads();
    // epilogue: coalesced global atomic fold of this block's exact int sums
    for (int i = t; i < SCN; i += 256) atomicAdd(&gx[s * SCN + i], facc_x[i]);
    for (int i = t; i < SCN; i += 256) atomicAdd(&gyz[s * SCN + i], facc_yz[i]);
    if (t == 0)
        atomicAdd(&energy[__float_as_int(slab[0].w)],
                  ered[0] + ered[2] + ered[4] + ered[6]);
    if (t == 1)
        atomicAdd(&energy[__float_as_int(slab[SCN - 1].w)],
                  ered[1] + ered[3] + ered[5] + ered[7]);
}

// ---------------------------------------------------------------------------
// P3: convert — int accumulators -> float forces. 3N coalesced writes.
__global__ __launch_bounds__(256) void convert_kernel(
    const int* __restrict__ gx,
    const unsigned long long* __restrict__ gyz,
    float* __restrict__ forces, int N)
{
    const int idx = blockIdx.x * 256 + threadIdx.x;   // over 3N = 300000
    if (idx >= 3 * N) return;
    const int n = idx / 3, c = idx - 3 * n;
    int v;
    if (c == 0)      v = gx[n];
    else if (c == 1) v = (int)(unsigned int)(gyz[n] & 0xffffffffull);
    else             v = (int)(unsigned int)(gyz[n] >> 32);
    forces[idx] = (float)v * FINV;
}

// ---------------------------------------------------------------------------
extern "C" void kernel_launch(void* const* d_in, const int* in_sizes, int n_in,
                              void* d_out, int out_size, void* d_ws, size_t ws_size,
                              hipStream_t stream) {
    const float* pos   = (const float*)d_in[0];
    const int*   ei    = (const int*)d_in[1];
    const int*   batch = (const int*)d_in[2];

    const int E = in_sizes[1] / 2;     // 3200000
    const int N = in_sizes[0] / 3;     // 100000 = NSC*SCN

    float* energy = (float*)d_out;
    float* forces = (float*)d_out + NUM_GRAPHS;

    const int per_block = (E + SB - 1) / SB;   // 6250; <= BITER*1024

    // ws: pos4 1.6 | recs 41.9 | counts 0.33 | gx 0.4 | gyz 0.8 MB  (~45 MB)
    char* w = (char*)d_ws;
    float4* pos4 = (float4*)w;
    size_t off = (size_t)N * 16;
    unsigned int* recs = (unsigned int*)(w + off);
    off += (size_t)SB * NSC * CAP * 4;
    int* counts = (int*)(w + off);
    off += (size_t)SB * NSC * 4;
    int* gx = (int*)(w + off);
    off += (size_t)N * 4;
    unsigned long long* gyz = (unsigned long long*)(w + off);

    // pack + all zeroing fused into bin's prologue: 3 dispatches total.
    bin_kernel<<<SB, 1024, 0, stream>>>(pos, batch, pos4, energy, gx, gyz,
                                        ei, recs, counts, N, E, per_block);

    accumulate_kernel<16><<<NSC * 16, 256, 0, stream>>>(
        pos4, recs, counts, energy, gx, gyz);

    convert_kernel<<<(3 * N + 255) / 256, 256, 0, stream>>>(
        gx, gyz, forces, N);
}

// Round 17
// 142.337 us; speedup vs baseline: 1.0644x; 1.0644x over previous
//
#include <hip/hip_runtime.h>

#define NUM_GRAPHS 64
#define NSC 160                 // sub-chunks; N = 100000 = 160 * 625
#define SCN 625                 // nodes per sub-chunk (10-bit local id)
#define XPAD 628                // padded per-partial stride (mult of 4)
#define SB 512                  // bin blocks (2 blocks/CU)
#define CAP 128                 // records per (bin-block, sub-chunk); mean 78, +5.7 sigma
#define SEGSTRIDE (NSC * CAP)   // record-region stride per segment
#define PBREC 12800             // per-block record buffer (2*6250 = 12500)
#define BITER 8                 // max grid-stride iters in bin (8*1024 >= 6250)
#define FSCALE 32768.0f         // fixed-point force scale (2^15)
#define FINV   (1.0f / 32768.0f)

// ---------------------------------------------------------------------------
// P1: two-pass LDS counting-sort bin with register-cached endpoints (proven
// R13/R15), with pack + energy-zero fused into the prologue. R16's global-
// atomic epilogue regressed (+8.5us) and is reverted: this is the measured-
// best 143.0us configuration. Record: own_loc(10b)|other(17b)<<10|eflag<<27.
__global__ __launch_bounds__(1024, 8) void bin_kernel(
    const float* __restrict__ pos, const int* __restrict__ batch,
    float4* __restrict__ pos4, float* __restrict__ energy,
    const int* __restrict__ ei,            // [2,E]
    unsigned int* __restrict__ recs,       // [SB][NSC][CAP]
    int* __restrict__ counts,              // [SB][NSC]
    int N, int E, int per_block)
{
    __shared__ unsigned int buf[PBREC];      // 50.0 KB
    __shared__ int hist[NSC];
    __shared__ int csr[NSC];
    __shared__ int cursor[NSC];
    __shared__ int scan_s[NSC];

    const int t = threadIdx.x, b = blockIdx.x;
    const int lane = t & 63, w = t >> 6;     // 16 waves
    const int e0 = b * per_block, e1 = min(E, e0 + per_block);

    // fused pack: first N global threads build pos4; block 0 zeroes energy.
    {
        const int gt = b * 1024 + t;
        if (gt < N) {
            float4 v;
            v.x = pos[3 * gt + 0];
            v.y = pos[3 * gt + 1];
            v.z = pos[3 * gt + 2];
            v.w = __int_as_float(batch[gt]);
            pos4[gt] = v;
        }
        if (b == 0 && t < NUM_GRAPHS) energy[t] = 0.f;
    }

    int civ[BITER], cjv[BITER];              // register-cached endpoints

    for (int i = t; i < NSC; i += 1024) hist[i] = 0;
    __syncthreads();

    // pass 1: histogram (both endpoints); cache iv/jv in registers
    #pragma unroll
    for (int it = 0; it < BITER; ++it) {
        const int e = e0 + t + it * 1024;
        if (e < e1) {
            const int iv = ei[e], jv = ei[E + e];
            civ[it] = iv; cjv[it] = jv;
            atomicAdd(&hist[iv / SCN], 1);
            atomicAdd(&hist[jv / SCN], 1);
        }
    }
    __syncthreads();

    // Hillis-Steele inclusive scan over 160 bins
    if (t < NSC) scan_s[t] = hist[t];
    __syncthreads();
    for (int d = 1; d < NSC; d <<= 1) {
        int v = 0;
        if (t < NSC && t >= d) v = scan_s[t - d];
        __syncthreads();
        if (t < NSC) scan_s[t] += v;
        __syncthreads();
    }
    if (t < NSC) {
        const int excl = scan_s[t] - hist[t];
        csr[t] = excl;
        cursor[t] = excl;
    }
    __syncthreads();

    // pass 2: scatter records into LDS at exact offsets (endpoints from regs)
    #pragma unroll
    for (int it = 0; it < BITER; ++it) {
        const int e = e0 + t + it * 1024;
        if (e < e1) {
            const int iv = civ[it], jv = cjv[it];
            const int si = iv / SCN, sj = jv / SCN;
            const int s1 = atomicAdd(&cursor[si], 1);
            buf[s1] = (unsigned int)(iv - si * SCN) | ((unsigned int)jv << 10) | (1u << 27);
            const int s2 = atomicAdd(&cursor[sj], 1);
            buf[s2] = (unsigned int)(jv - sj * SCN) | ((unsigned int)iv << 10);
        }
    }
    __syncthreads();

    // flush: wave per bin — contiguous LDS reads, coalesced global writes
    unsigned int* dst0 = recs + (size_t)b * NSC * CAP;
    for (int s = w; s < NSC; s += 16) {
        const int base = csr[s];
        const int cnt  = min(hist[s], CAP);
        for (int k = lane; k < cnt; k += 64)
            dst0[s * CAP + k] = buf[base + k];
        if (lane == 0) counts[b * NSC + s] = cnt;
    }
}

// ---------------------------------------------------------------------------
// P2: accumulate — R11/R13/R15's proven drain (x via u32 LDS atomic, y/z
// packed u64; measured 57us). Partials epilogue (R16's global-atomic fold
// regressed and is reverted).
template<int G>
__global__ __launch_bounds__(256, 8) void accumulate_kernel(
    const float4* __restrict__ pos4,
    const unsigned int* __restrict__ recs,
    const int* __restrict__ counts,
    float* __restrict__ energy,                // d_out[0..63], pre-zeroed
    int* __restrict__ xpart,                   // [NSC*G][XPAD] int
    unsigned long long* __restrict__ yzpart)   // [NSC*G][XPAD] u64
{
    __shared__ float4 slab[SCN];
    __shared__ __align__(16) int facc_x[XPAD];
    __shared__ __align__(16) unsigned long long facc_yz[XPAD];
    __shared__ float ered[8];              // 4 waves x {e_lo, e_hi}

    const int t    = threadIdx.x;
    const int lane = t & 63;
    const int w    = t >> 6;               // 4 waves
    const int s    = blockIdx.x % NSC;     // stride-160 -> same XCD (160%8==0)
    const int g    = blockIdx.x / NSC;

    constexpr int SPB   = SB / G;          // segments per block: 64 / 32
    constexpr int SPW   = SPB / 4;         // segments per wave:  16 / 8
    constexpr int NPASS = (SPW + 7) / 8;   // 8-segment passes:    2 / 1

    for (int i = t; i < SCN; i += 256) slab[i] = pos4[s * SCN + i];
    for (int i = 4 * t; i < XPAD; i += 1024) {
        int4 z = {0, 0, 0, 0};
        *(int4*)&facc_x[i] = z;
    }
    for (int i = 4 * t; i < 2 * XPAD; i += 1024) {
        int4 z = {0, 0, 0, 0};
        *(int4*)&((int*)facc_yz)[i] = z;
    }
    __syncthreads();

    const int gmin_i = __float_as_int(slab[0].w);
    float e_lo = 0.f, e_hi = 0.f;          // energy for gmin / gmax

    for (int pass = 0; pass < NPASS; ++pass) {
        const int seg0 = g * SPB + w * SPW + pass * 8;
        int v = (lane < 8) ? counts[(seg0 + lane) * NSC + s] : 0;
        #pragma unroll
        for (int d = 1; d < 8; d <<= 1) {
            const int u = __shfl_up(v, d);
            if (lane >= d) v += u;
        }
        const int b0 = __shfl(v, 0), b1 = __shfl(v, 1), b2 = __shfl(v, 2),
                  b3 = __shfl(v, 3), b4 = __shfl(v, 4), b5 = __shfl(v, 5),
                  b6 = __shfl(v, 6);
        const int tot = __shfl(v, 7);
        const unsigned int* bp = recs + ((size_t)seg0 * NSC + s) * CAP;

        for (int base = 0; base < tot; base += 256) {
            unsigned int rec[4];
            bool  val[4];
            int   a[4];
            float4 pb[4];
            // phase 1: record loads (coalesced within runs)
            #pragma unroll
            for (int u = 0; u < 4; ++u) {
                const int r = base + lane + (u << 6);
                val[u] = r < tot;
                if (val[u]) {
                    const int k = (r >= b0) + (r >= b1) + (r >= b2) + (r >= b3)
                                + (r >= b4) + (r >= b5) + (r >= b6);
                    int prev = 0;
                    prev = (k > 0) ? b0 : prev; prev = (k > 1) ? b1 : prev;
                    prev = (k > 2) ? b2 : prev; prev = (k > 3) ? b3 : prev;
                    prev = (k > 4) ? b4 : prev; prev = (k > 5) ? b5 : prev;
                    prev = (k > 6) ? b6 : prev;
                    rec[u] = bp[(size_t)k * SEGSTRIDE + (r - prev)];
                }
            }
            // phase 2: divergent pos4 gathers (L2-resident)
            #pragma unroll
            for (int u = 0; u < 4; ++u) {
                if (val[u]) {
                    a[u]  = (int)(rec[u] & 1023);
                    pb[u] = pos4[(rec[u] >> 10) & 0x1FFFF];
                }
            }
            // phase 3: compute + 2 int LDS atomics (x u32; y,z packed u64)
            #pragma unroll
            for (int u = 0; u < 4; ++u) {
                if (val[u]) {
                    const float4 pa = slab[a[u]];
                    const float dx = pa.x - pb[u].x;
                    const float dy = pa.y - pb[u].y;
                    const float dz = pa.z - pb[u].z;
                    const float r2  = fmaxf(dx*dx + dy*dy + dz*dz, 1e-24f);
                    const float inv = __builtin_amdgcn_rsqf(r2);  // 1/d
                    const float sc  = 1.0f - inv;                 // delta/d
                    const int xq = __float2int_rn(-sc * dx * FSCALE);
                    const int yq = __float2int_rn(-sc * dy * FSCALE);
                    const int zq = __float2int_rn(-sc * dz * FSCALE);
                    atomicAdd(&facc_x[a[u]], xq);
                    const unsigned long long pk =
                        ((unsigned long long)(unsigned int)zq << 32)
                        + (unsigned long long)(unsigned int)yq;
                    atomicAdd(&facc_yz[a[u]], pk);
                    if (rec[u] >> 27) {                           // energy once/edge
                        const float delta = r2 * inv - 1.0f;      // d - 1
                        const float e = 0.5f * delta * delta;
                        if (__float_as_int(pa.w) == gmin_i) e_lo += e;
                        else                                e_hi += e;
                    }
                }
            }
        }
    }

    // block-reduce the two energy registers; 2 global atomics per block
    #pragma unroll
    for (int d = 32; d > 0; d >>= 1) {
        e_lo += __shfl_down(e_lo, d);
        e_hi += __shfl_down(e_hi, d);
    }
    if (lane == 0) { ered[2 * w] = e_lo; ered[2 * w + 1] = e_hi; }

    __syncthreads();
    int* xdst = xpart + (size_t)(s * G + g) * XPAD;
    unsigned long long* zdst = yzpart + (size_t)(s * G + g) * XPAD;
    for (int i = t; i < SCN; i += 256) xdst[i] = facc_x[i];
    for (int i = t; i < SCN; i += 256) zdst[i] = facc_yz[i];
    if (t == 0)
        atomicAdd(&energy[__float_as_int(slab[0].w)],
                  ered[0] + ered[2] + ered[4] + ered[6]);
    if (t == 1)
        atomicAdd(&energy[__float_as_int(slab[SCN - 1].w)],
                  ered[1] + ered[3] + ered[5] + ered[7]);
}

// ---------------------------------------------------------------------------
// P3: one thread per node: unpack + exact int sums over G partials.
template<int G>
__global__ __launch_bounds__(256) void reduce_kernel(
    const int* __restrict__ xpart,
    const unsigned long long* __restrict__ yzpart,
    float* __restrict__ forces, int N)
{
    const int n = blockIdx.x * 256 + threadIdx.x;
    if (n >= N) return;
    const int s = n / SCN, a = n - s * SCN;
    int sx = 0, sy = 0, sz = 0;
    #pragma unroll
    for (int g = 0; g < G; ++g) {
        const size_t p = (size_t)(s * G + g) * XPAD + a;
        sx += xpart[p];
        const unsigned long long v = yzpart[p];
        sy += (int)(unsigned int)(v & 0xffffffffull);
        sz += (int)(unsigned int)(v >> 32);
    }
    forces[3 * n + 0] = (float)sx * FINV;
    forces[3 * n + 1] = (float)sy * FINV;
    forces[3 * n + 2] = (float)sz * FINV;
}

// ---------------------------------------------------------------------------
extern "C" void kernel_launch(void* const* d_in, const int* in_sizes, int n_in,
                              void* d_out, int out_size, void* d_ws, size_t ws_size,
                              hipStream_t stream) {
    const float* pos   = (const float*)d_in[0];
    const int*   ei    = (const int*)d_in[1];
    const int*   batch = (const int*)d_in[2];

    const int E = in_sizes[1] / 2;     // 3200000
    const int N = in_sizes[0] / 3;     // 100000 = NSC*SCN

    float* energy = (float*)d_out;
    float* forces = (float*)d_out + NUM_GRAPHS;

    const int per_block = (E + SB - 1) / SB;   // 6250; <= BITER*1024

    // ws: pos4 1.6 | recs 41.9 | counts 0.33 | xpart G*0.4 | yzpart G*0.8 MB
    char* w = (char*)d_ws;
    float4* pos4 = (float4*)w;
    size_t off = (size_t)N * 16;
    unsigned int* recs = (unsigned int*)(w + off);
    off += (size_t)SB * NSC * CAP * 4;
    int* counts = (int*)(w + off);
    off += (size_t)SB * NSC * 4;
    int* xpart = (int*)(w + off);
    const size_t xbytes16 = (size_t)NSC * 16 * XPAD * 4;
    const size_t xbytes8  = (size_t)NSC * 8  * XPAD * 4;

    // pack + energy-zero fused into bin's prologue: 3 dispatches total.
    bin_kernel<<<SB, 1024, 0, stream>>>(pos, batch, pos4, energy,
                                        ei, recs, counts, N, E, per_block);

    const size_t need16 = off + xbytes16 + (size_t)NSC * 16 * XPAD * 8;
    if (ws_size >= need16) {
        unsigned long long* yzpart = (unsigned long long*)((char*)xpart + xbytes16);
        accumulate_kernel<16><<<NSC * 16, 256, 0, stream>>>(
            pos4, recs, counts, energy, xpart, yzpart);
        reduce_kernel<16><<<(N + 255) / 256, 256, 0, stream>>>(
            xpart, yzpart, forces, N);
    } else {
        unsigned long long* yzpart = (unsigned long long*)((char*)xpart + xbytes8);
        accumulate_kernel<8><<<NSC * 8, 256, 0, stream>>>(
            pos4, recs, counts, energy, xpart, yzpart);
        reduce_kernel<8><<<(N + 255) / 256, 256, 0, stream>>>(
            xpart, yzpart, forces, N);
    }
}